// Round 1
// baseline (84.621 us; speedup 1.0000x reference)
//
#include <hip/hip_runtime.h>

// PartialMatchingLoss: mean over (b,m) of min_n ||partial[b,m] - completed[b,n]||
// B=8, M=4096 (partial), N=8192 (completed), D=3, fp32.
//
// Strategy: minimize f(n) = 0.5*||c||^2 - p.c  (3 FMA + 1 min per pair), then
// d2 = 2*f_min + ||p||^2, clamped, sqrt'd and averaged in a reduce pass.
// N split into NC chunks so the grid saturates 256 CUs; per-chunk d2 written
// to workspace (coalesced, no atomics), reduced in kernel 2.

constexpr int B  = 8;
constexpr int N  = 8192;   // completed points per batch
constexpr int M  = 4096;   // partial points per batch
constexpr int NT = 256;    // threads per block (main kernel)
constexpr int TP = 8;      // partial points per thread
constexpr int MBLK = NT * TP;      // 2048 partial points per block
constexpr int MC   = M / MBLK;     // 2 m-chunks
constexpr int NBLK = 256;          // completed points per block chunk
constexpr int NC   = N / NBLK;     // 32 n-chunks
constexpr int TOTAL_PM = B * M;    // 32768 rows

__global__ __launch_bounds__(NT) void pml_main(const float* __restrict__ completed,
                                               const float* __restrict__ partial,
                                               float* __restrict__ ws) {
    __shared__ float4 cs[NBLK];
    const int t     = threadIdx.x;
    const int b     = blockIdx.z;
    const int mBase = blockIdx.y * MBLK;
    const int nBase = blockIdx.x * NBLK;

    // Stage this block's completed chunk into LDS as {x, y, z, 0.5*|c|^2}.
    {
        const float* cp = completed + (size_t)(b * N + nBase + t) * 3;
        float x = cp[0], y = cp[1], z = cp[2];
        cs[t] = make_float4(x, y, z, 0.5f * (x * x + y * y + z * z));
    }
    __syncthreads();

    const int m0 = mBase + t * TP;
    const float* pp = partial + (size_t)(b * M + m0) * 3;

    float nx[TP], ny[TP], nz[TP], fm[TP];
#pragma unroll
    for (int p = 0; p < TP; ++p) {
        float x = pp[3 * p + 0];
        float y = pp[3 * p + 1];
        float z = pp[3 * p + 2];
        nx[p] = -x; ny[p] = -y; nz[p] = -z;
        fm[p] = 3.402823466e38f;
    }

#pragma unroll 2
    for (int j = 0; j < NBLK; ++j) {
        float4 c = cs[j];   // wave-uniform address -> LDS broadcast, conflict-free
#pragma unroll
        for (int p = 0; p < TP; ++p) {
            float f = fmaf(nx[p], c.x, fmaf(ny[p], c.y, fmaf(nz[p], c.z, c.w)));
            fm[p] = fminf(fm[p], f);
        }
    }

    // d2 = 2*f_min + |p|^2, clamped at 0 (monotone; safe to clamp per-chunk).
    float o[TP];
#pragma unroll
    for (int p = 0; p < TP; ++p) {
        float x = nx[p], y = ny[p], z = nz[p];
        float psq = x * x + y * y + z * z;
        o[p] = fmaxf(fmaf(2.0f, fm[p], psq), 0.0f);
    }

    // ws layout: [nc][b*M + m] -> each thread writes 8 contiguous floats.
    float4* wsv = (float4*)(ws + (size_t)blockIdx.x * TOTAL_PM + b * M + m0);
    wsv[0] = make_float4(o[0], o[1], o[2], o[3]);
    wsv[1] = make_float4(o[4], o[5], o[6], o[7]);
}

constexpr int RBLOCKS = 64;
constexpr int RT      = 256;
constexpr int RPT     = TOTAL_PM / (RBLOCKS * RT);  // 2 rows per thread

__global__ __launch_bounds__(RT) void pml_reduce(const float* __restrict__ ws,
                                                 float* __restrict__ out) {
    const int gid = blockIdx.x * RT + threadIdx.x;
    float s = 0.0f;
#pragma unroll
    for (int k = 0; k < RPT; ++k) {
        int idx = gid + k * (RBLOCKS * RT);
        float m = 3.402823466e38f;
#pragma unroll
        for (int c = 0; c < NC; ++c)
            m = fminf(m, ws[(size_t)c * TOTAL_PM + idx]);   // coalesced per c
        s += sqrtf(m);
    }
    // wave (64-lane) reduction
#pragma unroll
    for (int off = 32; off > 0; off >>= 1) s += __shfl_down(s, off);

    __shared__ float red[RT / 64];
    const int lane = threadIdx.x & 63;
    const int wid  = threadIdx.x >> 6;
    if (lane == 0) red[wid] = s;
    __syncthreads();
    if (threadIdx.x == 0) {
        float tot = red[0] + red[1] + red[2] + red[3];
        atomicAdd(out, tot * (1.0f / (float)TOTAL_PM));
    }
}

__global__ void pml_zero(float* out) { out[0] = 0.0f; }

extern "C" void kernel_launch(void* const* d_in, const int* in_sizes, int n_in,
                              void* d_out, int out_size, void* d_ws, size_t ws_size,
                              hipStream_t stream) {
    const float* completed = (const float*)d_in[0];  // (8, 8192, 3)
    const float* partial   = (const float*)d_in[1];  // (8, 4096, 3)
    float* out = (float*)d_out;
    float* ws  = (float*)d_ws;   // needs NC * TOTAL_PM * 4 = 4 MB

    pml_zero<<<1, 1, 0, stream>>>(out);

    dim3 grid(NC, MC, B);        // (32, 2, 8) = 512 blocks
    pml_main<<<grid, NT, 0, stream>>>(completed, partial, ws);

    pml_reduce<<<RBLOCKS, RT, 0, stream>>>(ws, out);
}